// Round 4
// baseline (469.058 us; speedup 1.0000x reference)
//
#include <hip/hip_runtime.h>
#include <stdint.h>

// Problem constants (from reference) — all inputs/outputs are FP32.
#define T_DIM 16
#define M_DIM 1024
#define N_NODES 10000
#define NB 100
#define N_IN 8000
#define KI 4096             // i dimension (4*M)
#define KP 8192             // interleaved i' = 2*i + o (memory-contiguous axis of weight)
#define CHUNKS 8
#define I_CHUNK (KI / CHUNKS)        // 512 i-values per chunk
#define M_CHUNK (I_CHUNK / 4)        // 128 m-values per chunk
#define STEPS ((KP / CHUNKS) / 32)   // 32 MFMA k-steps per chunk
#define PITCH (I_CHUNK + 4)          // 516 shorts row pitch (8B aligned; 258 words %32=2 -> conflict-free)
#define TILES 625                    // worst-case tiles over all 10000 nodes
#define SLAB (N_NODES * T_DIM * 2)   // 320000 floats per chunk-slab

typedef short short8 __attribute__((ext_vector_type(8)));
typedef float f32x4 __attribute__((ext_vector_type(4)));

__device__ __forceinline__ unsigned int fbits(float f) {
    return __builtin_bit_cast(unsigned int, f);
}
// fp32 -> bf16 (RNE), result in low 16 bits
__device__ __forceinline__ unsigned int bf16rne(unsigned int u) {
    return (u + 0x7FFFu + ((u >> 16) & 1u)) >> 16;
}
__device__ __forceinline__ unsigned int pack2bf(float a, float b) {
    return bf16rne(fbits(a)) | (bf16rne(fbits(b)) << 16);
}
// HW packed fp32->bf16 (RNE): low16 = cvt(a), high16 = cvt(b). Bitwise
// identical to pack2bf for finite inputs; 1 VALU op instead of ~10.
__device__ __forceinline__ unsigned int cvtpk(float a, float b) {
    unsigned int r;
    asm("v_cvt_pk_bf16_f32 %0, %1, %2" : "=v"(r) : "v"(a), "v"(b));
    return r;
}

// ---------------------------------------------------------------------------
// Dedup: flag all referenced nodes in LDS, compact into a dense id list.
// Single block (1024 threads). Ballot-based compaction: one atomicAdd per
// wave per stride-iteration (~160 total) instead of one per set flag (~5.7k).
// Side effect: list is (piecewise) sorted -> each GEMM wave's 16 nodes are
// near-consecutive -> weight reads get DRAM/L2 spatial locality.
// ---------------------------------------------------------------------------
__global__ __launch_bounds__(1024) void dedup_kernel(
    const int* __restrict__ node_in,
    const int* __restrict__ top, const int* __restrict__ bottom,
    const int* __restrict__ left, const int* __restrict__ right,
    int* __restrict__ counter, int* __restrict__ list)
{
    __shared__ int flags[N_NODES];       // 40 KB
    __shared__ int lcnt;
    const int tid = threadIdx.x;
    for (int i = tid; i < N_NODES; i += 1024) flags[i] = 0;
    if (tid == 0) lcnt = 0;
    __syncthreads();
    for (int i = tid; i < N_IN + 4 * NB; i += 1024) {
        int v;
        if (i < N_IN)              v = node_in[i];
        else if (i < N_IN + NB)    v = top[i - N_IN];
        else if (i < N_IN + 2*NB)  v = bottom[i - N_IN - NB];
        else if (i < N_IN + 3*NB)  v = left[i - N_IN - 2*NB];
        else                       v = right[i - N_IN - 3*NB];
        flags[v - 1] = 1;
    }
    __syncthreads();
    const int lane = tid & 63;
    for (int i = tid; i < N_NODES; i += 1024) {
        int f = flags[i];
        unsigned long long mask = __ballot(f);
        int prefix = __popcll(mask & ((1ull << lane) - 1ull));
        int base = 0;
        if (lane == 0) base = atomicAdd(&lcnt, (int)__popcll(mask));
        base = __shfl(base, 0);
        if (f) list[base + prefix] = i;
    }
    __syncthreads();
    if (tid == 0) *counter = lcnt;
}

// ---------------------------------------------------------------------------
// GEMM over REFERENCED nodes only: f[n,t,o] = sum_i x_out[t,i] * W[n,i,o]
// (fp32 in, fp32 acc, bf16 MFMA). K' = 8192 interleaved (i,o). B fragment =
// 8 consecutive fp32 weights/lane converted to bf16 in-register (HW cvt_pk).
// A0/A1 = x_out with zeros at odd/even k' slots -> o=0 / o=1 accumulators
// (two MFMAs share one weight load). Each wave owns one (16-node tile from
// `list`, K-chunk) pair; partials go to per-chunk slabs with plain stores.
// 4-deep software-pipelined weight prefetch (8 outstanding float4 loads/lane)
// — the kernel runs at ~2.8 waves/SIMD, so per-wave MLP is the only
// latency-hiding lever. Weight loads are PLAIN CACHED (nt reverted: the
// lo/hi pair of each node's 128B line relies on L1/L2 hits; nt would force
// 2x HBM re-fetch of every line).
// grid = (157 tile-groups, 8 K-chunks) x 256 threads (4 waves, 1 tile each);
// blocks fully past the compacted count exit before staging.
// ---------------------------------------------------------------------------
__global__ __launch_bounds__(256) void gemm_kernel(
    const float* __restrict__ x,       // fp32 [16][3][1024]
    const float* __restrict__ weight,  // fp32 [10000][4096][2]
    const int* __restrict__ list,      // compacted referenced node ids
    const int* __restrict__ counter,   // number of referenced nodes
    float* __restrict__ fws)           // fp32 [8][10000][16][2] partial slabs
{
    __shared__ unsigned short lds_x[T_DIM * PITCH];   // x_out chunk as bf16

    const int tid = threadIdx.x;
    const int chunk = blockIdx.y;

    const int cnt = *counter;                 // block-uniform scalar
    if (blockIdx.x * 64 >= cnt) return;       // whole block unneeded (4 waves x 16)

    // Stage this chunk's x_out[t, i] into LDS as bf16.
    // x_out[t, 4m + {0,1,2,3}] = [x[t,0,m], x[t,2,m], x[t,2,m], x[t,1,m]]
    for (int q = tid; q < T_DIM * M_CHUNK; q += 256) {
        int t = q >> 7;            // M_CHUNK == 128 per t
        int mloc = q & 127;
        int m = chunk * M_CHUNK + mloc;
        const float* xb = x + t * 3 * M_DIM + m;
        float v0 = xb[0];
        float v1 = xb[M_DIM];
        float v2 = xb[2 * M_DIM];
        unsigned int w0 = cvtpk(v0, v2);     // slots 4m+0, 4m+1
        unsigned int w1 = cvtpk(v2, v1);     // slots 4m+2, 4m+3
        *(uint2*)&lds_x[t * PITCH + mloc * 4] = make_uint2(w0, w1);
    }
    __syncthreads();

    const int wave = tid >> 6;
    const int lane = tid & 63;
    const int tile = blockIdx.x * 4 + wave;
    if (tile * 16 >= cnt) return;             // whole wave unneeded

    const int col = lane & 15;   // n-slot within tile (B/C col)
    const int quad = lane >> 4;  // k-group
    const int idx = tile * 16 + col;
    const int n = (idx < cnt) ? list[idx] : 0;

    // B source: lane holds W'[k' = quad*8 + j][n], j contiguous in memory (fp32).
    const float* wp =
        weight + (size_t)n * KP + (size_t)chunk * (KP / CHUNKS) + quad * 8;
    // A source: 4 consecutive bf16 x_out values for t = lane&15.
    const unsigned short* xrow = &lds_x[(lane & 15) * PITCH + quad * 4];

    f32x4 acc0 = {0.f, 0.f, 0.f, 0.f};
    f32x4 acc1 = {0.f, 0.f, 0.f, 0.f};

#define GSTEP(S, LO, HI) do {                                               \
        union { unsigned int ui[4]; short8 v; } Bu;                         \
        Bu.ui[0] = cvtpk((LO).x, (LO).y);                                   \
        Bu.ui[1] = cvtpk((LO).z, (LO).w);                                   \
        Bu.ui[2] = cvtpk((HI).x, (HI).y);                                   \
        Bu.ui[3] = cvtpk((HI).z, (HI).w);                                   \
        uint2 u = *(const uint2*)(xrow + (S) * 16);                         \
        union { unsigned int ui[4]; short8 v; } A0u, A1u;                   \
        A0u.ui[0] = u.x & 0xFFFFu;      A0u.ui[1] = u.x >> 16;              \
        A0u.ui[2] = u.y & 0xFFFFu;      A0u.ui[3] = u.y >> 16;              \
        A1u.ui[0] = u.x << 16;          A1u.ui[1] = u.x & 0xFFFF0000u;      \
        A1u.ui[2] = u.y << 16;          A1u.ui[3] = u.y & 0xFFFF0000u;      \
        acc0 = __builtin_amdgcn_mfma_f32_16x16x32_bf16(A0u.v, Bu.v, acc0, 0, 0, 0); \
        acc1 = __builtin_amdgcn_mfma_f32_16x16x32_bf16(A1u.v, Bu.v, acc1, 0, 0, 0); \
    } while (0)

    // 4-deep software pipeline, named registers only (no runtime-indexed
    // arrays -> stays in VGPRs). 8 float4 loads in flight per lane.
    float4 p0l = *(const float4*)(wp + 0 * 32), p0h = *(const float4*)(wp + 0 * 32 + 4);
    float4 p1l = *(const float4*)(wp + 1 * 32), p1h = *(const float4*)(wp + 1 * 32 + 4);
    float4 p2l = *(const float4*)(wp + 2 * 32), p2h = *(const float4*)(wp + 2 * 32 + 4);
    float4 p3l = *(const float4*)(wp + 3 * 32), p3h = *(const float4*)(wp + 3 * 32 + 4);

    #pragma unroll 2
    for (int s = 0; s < STEPS; s += 4) {
        float4 lo, hi;
        lo = p0l; hi = p0h;
        if (s + 4 < STEPS) {
            p0l = *(const float4*)(wp + (s + 4) * 32);
            p0h = *(const float4*)(wp + (s + 4) * 32 + 4);
        }
        GSTEP(s + 0, lo, hi);
        lo = p1l; hi = p1h;
        if (s + 5 < STEPS) {
            p1l = *(const float4*)(wp + (s + 5) * 32);
            p1h = *(const float4*)(wp + (s + 5) * 32 + 4);
        }
        GSTEP(s + 1, lo, hi);
        lo = p2l; hi = p2h;
        if (s + 6 < STEPS) {
            p2l = *(const float4*)(wp + (s + 6) * 32);
            p2h = *(const float4*)(wp + (s + 6) * 32 + 4);
        }
        GSTEP(s + 2, lo, hi);
        lo = p3l; hi = p3h;
        if (s + 7 < STEPS) {
            p3l = *(const float4*)(wp + (s + 7) * 32);
            p3h = *(const float4*)(wp + (s + 7) * 32 + 4);
        }
        GSTEP(s + 3, lo, hi);
    }
#undef GSTEP

    // C/D layout: col = lane&15, row(t) = quad*4 + reg.
    // Plain float2 stores into this chunk's slab (each addr written once;
    // padding lanes duplicate node 0 with identical values — benign).
    float* slab = fws + (size_t)chunk * SLAB;
    #pragma unroll
    for (int r = 0; r < 4; ++r) {
        int t = quad * 4 + r;
        *(float2*)&slab[((size_t)n * T_DIM + t) * 2] = make_float2(acc0[r], acc1[r]);
    }
}

// ---------------------------------------------------------------------------
// Gather f_in = f[node_in-1] (256000 fp32, float4-vectorized: 8 threads/node)
// + boundary sums f_b (96 fp32). f = sum of the 8 chunk slabs (LLC-resident).
// ---------------------------------------------------------------------------
__global__ __launch_bounds__(256) void gather_kernel(
    const float* __restrict__ fws,
    const int* __restrict__ node_in,
    const int* __restrict__ top, const int* __restrict__ bottom,
    const int* __restrict__ left, const int* __restrict__ right,
    float* __restrict__ out)
{
    const int tid = threadIdx.x;
    if (blockIdx.x < 250) {
        int e4 = blockIdx.x * 1024 + tid * 4;  // element base; 256000 = 250*1024
        int j = e4 >> 5;                       // node_in index (32 elems/node)
        int rem = e4 & 31;                     // (t*2+o) base, 16B aligned
        size_t base = (size_t)(node_in[j] - 1) * 32 + rem;
        float4 v = {0.f, 0.f, 0.f, 0.f};
        #pragma unroll
        for (int c = 0; c < CHUNKS; ++c) {
            float4 s = *(const float4*)&fws[c * (size_t)SLAB + base];
            v.x += s.x; v.y += s.y; v.z += s.z; v.w += s.w;
        }
        *(float4*)&out[e4] = v;
    } else {
        __shared__ float red[256];
        __shared__ float sums[64];
        const int l = tid >> 6;                // 0=top 1=bottom 2=left 3=right
        const int t = (tid >> 2) & 15;
        const int p = tid & 3;
        // Select chain instead of runtime-indexed pointer array (rule #20:
        // dyn-indexed local arrays can be allocated in scratch).
        const int* lp = (l == 0) ? top : (l == 1) ? bottom : (l == 2) ? left : right;
        const int osel = (l < 2) ? 1 : 0;
        float s = 0.f;
        for (int idx = p; idx < NB; idx += 4) {
            size_t base = (size_t)(lp[idx] - 1) * 32 + t * 2 + osel;
            #pragma unroll
            for (int c = 0; c < CHUNKS; ++c) s += fws[c * (size_t)SLAB + base];
        }
        red[tid] = s;
        __syncthreads();
        if (p == 0)
            sums[tid >> 2] = red[tid] + red[tid + 1] + red[tid + 2] + red[tid + 3];
        __syncthreads();
        if (tid < 96) {
            int row = tid >> 4;                // 0..5 -> [top,bot,left,right,t+b,l+r]
            int tt = tid & 15;
            float v;
            if (row < 4)       v = sums[row * 16 + tt];
            else if (row == 4) v = sums[0 * 16 + tt] + sums[1 * 16 + tt];
            else               v = sums[2 * 16 + tt] + sums[3 * 16 + tt];
            out[256000 + tid] = v;
        }
    }
}

extern "C" void kernel_launch(void* const* d_in, const int* in_sizes, int n_in,
                              void* d_out, int out_size, void* d_ws, size_t ws_size,
                              hipStream_t stream)
{
    const float* x      = (const float*)d_in[0];
    const float* weight = (const float*)d_in[1];
    const int* node_in = (const int*)d_in[2];
    const int* top     = (const int*)d_in[3];
    const int* bottom  = (const int*)d_in[4];
    const int* left    = (const int*)d_in[5];
    const int* right   = (const int*)d_in[6];

    float* fws  = (float*)d_ws;                        // 8 slabs x 1.28 MB
    int*   cnt  = (int*)(fws + (size_t)CHUNKS * SLAB); // 1 int
    int*   list = cnt + 1;                             // up to 10000 ids
    float* out  = (float*)d_out;                       // 256000 f_in + 96 f_b

    dedup_kernel<<<1, 1024, 0, stream>>>(node_in, top, bottom, left, right, cnt, list);

    dim3 grid((TILES + 3) / 4, CHUNKS);                // 157 x 8 (worst case)
    gemm_kernel<<<grid, 256, 0, stream>>>(x, weight, list, cnt, fws);
    gather_kernel<<<251, 256, 0, stream>>>(fws, node_in, top, bottom, left, right, out);
}

// Round 5
// 463.198 us; speedup vs baseline: 1.0127x; 1.0127x over previous
//
#include <hip/hip_runtime.h>
#include <stdint.h>

// Problem constants (from reference) — all inputs/outputs are FP32.
#define T_DIM 16
#define M_DIM 1024
#define N_NODES 10000
#define NB 100
#define N_IN 8000
#define KI 4096             // i dimension (4*M)
#define KP 8192             // interleaved i' = 2*i + o (memory-contiguous axis of weight)
#define CHUNKS 16
#define I_CHUNK (KI / CHUNKS)        // 256 i-values per chunk
#define M_CHUNK (I_CHUNK / 4)        // 64 m-values per chunk
#define STEPS ((KP / CHUNKS) / 32)   // 16 MFMA k-steps per chunk
#define PITCH (I_CHUNK + 4)          // 260 shorts row pitch (130 words %32=2 -> same conflict-free pattern)
#define TILES 625                    // worst-case tiles over all 10000 nodes
#define SLAB (N_NODES * T_DIM * 2)   // 320000 floats per chunk-slab

typedef short short8 __attribute__((ext_vector_type(8)));
typedef float f32x4 __attribute__((ext_vector_type(4)));

__device__ __forceinline__ unsigned int fbits(float f) {
    return __builtin_bit_cast(unsigned int, f);
}
// fp32 -> bf16 (RNE), result in low 16 bits
__device__ __forceinline__ unsigned int bf16rne(unsigned int u) {
    return (u + 0x7FFFu + ((u >> 16) & 1u)) >> 16;
}
__device__ __forceinline__ unsigned int pack2bf(float a, float b) {
    return bf16rne(fbits(a)) | (bf16rne(fbits(b)) << 16);
}
// HW packed fp32->bf16 (RNE): low16 = cvt(a), high16 = cvt(b). Bitwise
// identical to pack2bf for finite inputs; 1 VALU op instead of ~10.
__device__ __forceinline__ unsigned int cvtpk(float a, float b) {
    unsigned int r;
    asm("v_cvt_pk_bf16_f32 %0, %1, %2" : "=v"(r) : "v"(a), "v"(b));
    return r;
}

// ---------------------------------------------------------------------------
// Dedup: flag all referenced nodes in LDS, compact into a dense id list.
// Single block (1024 threads). Ballot-based compaction: one atomicAdd per
// wave per stride-iteration (~160 total) instead of one per set flag (~5.7k).
// Side effect: list is (piecewise) sorted -> each GEMM wave's 16 nodes are
// near-consecutive -> weight reads get DRAM/L2 spatial locality.
// ---------------------------------------------------------------------------
__global__ __launch_bounds__(1024) void dedup_kernel(
    const int* __restrict__ node_in,
    const int* __restrict__ top, const int* __restrict__ bottom,
    const int* __restrict__ left, const int* __restrict__ right,
    int* __restrict__ counter, int* __restrict__ list)
{
    __shared__ int flags[N_NODES];       // 40 KB
    __shared__ int lcnt;
    const int tid = threadIdx.x;
    for (int i = tid; i < N_NODES; i += 1024) flags[i] = 0;
    if (tid == 0) lcnt = 0;
    __syncthreads();
    for (int i = tid; i < N_IN + 4 * NB; i += 1024) {
        int v;
        if (i < N_IN)              v = node_in[i];
        else if (i < N_IN + NB)    v = top[i - N_IN];
        else if (i < N_IN + 2*NB)  v = bottom[i - N_IN - NB];
        else if (i < N_IN + 3*NB)  v = left[i - N_IN - 2*NB];
        else                       v = right[i - N_IN - 3*NB];
        flags[v - 1] = 1;
    }
    __syncthreads();
    const int lane = tid & 63;
    for (int i = tid; i < N_NODES; i += 1024) {
        int f = flags[i];
        unsigned long long mask = __ballot(f);
        int prefix = __popcll(mask & ((1ull << lane) - 1ull));
        int base = 0;
        if (lane == 0) base = atomicAdd(&lcnt, (int)__popcll(mask));
        base = __shfl(base, 0);
        if (f) list[base + prefix] = i;
    }
    __syncthreads();
    if (tid == 0) *counter = lcnt;
}

// ---------------------------------------------------------------------------
// GEMM over REFERENCED nodes only: f[n,t,o] = sum_i x_out[t,i] * W[n,i,o]
// (fp32 in, fp32 acc, bf16 MFMA). K' = 8192 interleaved (i,o). B fragment =
// 8 consecutive fp32 weights/lane converted to bf16 in-register (HW cvt_pk).
// A0/A1 = x_out with zeros at odd/even k' slots -> o=0 / o=1 accumulators
// (two MFMAs share one weight load). Each wave owns one (16-node tile from
// `list`, K-chunk) pair; partials go to per-chunk slabs with plain stores.
// CHUNKS=16 this round: ~5.6 waves/SIMD (was 2.8) — the discriminating
// experiment between "gemm latency-bound" (total should drop ~80 µs) and
// "harness-fill-dominated" (total unchanged). 4-deep software-pipelined
// weight prefetch (8 outstanding float4 loads/lane) retained.
// grid = (157 tile-groups, 16 K-chunks) x 256 threads (4 waves, 1 tile each);
// blocks fully past the compacted count exit before staging.
// ---------------------------------------------------------------------------
__global__ __launch_bounds__(256) void gemm_kernel(
    const float* __restrict__ x,       // fp32 [16][3][1024]
    const float* __restrict__ weight,  // fp32 [10000][4096][2]
    const int* __restrict__ list,      // compacted referenced node ids
    const int* __restrict__ counter,   // number of referenced nodes
    float* __restrict__ fws)           // fp32 [16][10000][16][2] partial slabs
{
    __shared__ unsigned short lds_x[T_DIM * PITCH];   // x_out chunk as bf16

    const int tid = threadIdx.x;
    const int chunk = blockIdx.y;

    const int cnt = *counter;                 // block-uniform scalar
    if (blockIdx.x * 64 >= cnt) return;       // whole block unneeded (4 waves x 16)

    // Stage this chunk's x_out[t, i] into LDS as bf16.
    // x_out[t, 4m + {0,1,2,3}] = [x[t,0,m], x[t,2,m], x[t,2,m], x[t,1,m]]
    for (int q = tid; q < T_DIM * M_CHUNK; q += 256) {
        int t = q >> 6;            // M_CHUNK == 64 per t
        int mloc = q & 63;
        int m = chunk * M_CHUNK + mloc;
        const float* xb = x + t * 3 * M_DIM + m;
        float v0 = xb[0];
        float v1 = xb[M_DIM];
        float v2 = xb[2 * M_DIM];
        unsigned int w0 = cvtpk(v0, v2);     // slots 4m+0, 4m+1
        unsigned int w1 = cvtpk(v2, v1);     // slots 4m+2, 4m+3
        *(uint2*)&lds_x[t * PITCH + mloc * 4] = make_uint2(w0, w1);
    }
    __syncthreads();

    const int wave = tid >> 6;
    const int lane = tid & 63;
    const int tile = blockIdx.x * 4 + wave;
    if (tile * 16 >= cnt) return;             // whole wave unneeded

    const int col = lane & 15;   // n-slot within tile (B/C col)
    const int quad = lane >> 4;  // k-group
    const int idx = tile * 16 + col;
    const int n = (idx < cnt) ? list[idx] : 0;

    // B source: lane holds W'[k' = quad*8 + j][n], j contiguous in memory (fp32).
    const float* wp =
        weight + (size_t)n * KP + (size_t)chunk * (KP / CHUNKS) + quad * 8;
    // A source: 4 consecutive bf16 x_out values for t = lane&15.
    const unsigned short* xrow = &lds_x[(lane & 15) * PITCH + quad * 4];

    f32x4 acc0 = {0.f, 0.f, 0.f, 0.f};
    f32x4 acc1 = {0.f, 0.f, 0.f, 0.f};

#define GSTEP(S, LO, HI) do {                                               \
        union { unsigned int ui[4]; short8 v; } Bu;                         \
        Bu.ui[0] = cvtpk((LO).x, (LO).y);                                   \
        Bu.ui[1] = cvtpk((LO).z, (LO).w);                                   \
        Bu.ui[2] = cvtpk((HI).x, (HI).y);                                   \
        Bu.ui[3] = cvtpk((HI).z, (HI).w);                                   \
        uint2 u = *(const uint2*)(xrow + (S) * 16);                         \
        union { unsigned int ui[4]; short8 v; } A0u, A1u;                   \
        A0u.ui[0] = u.x & 0xFFFFu;      A0u.ui[1] = u.x >> 16;              \
        A0u.ui[2] = u.y & 0xFFFFu;      A0u.ui[3] = u.y >> 16;              \
        A1u.ui[0] = u.x << 16;          A1u.ui[1] = u.x & 0xFFFF0000u;      \
        A1u.ui[2] = u.y << 16;          A1u.ui[3] = u.y & 0xFFFF0000u;      \
        acc0 = __builtin_amdgcn_mfma_f32_16x16x32_bf16(A0u.v, Bu.v, acc0, 0, 0, 0); \
        acc1 = __builtin_amdgcn_mfma_f32_16x16x32_bf16(A1u.v, Bu.v, acc1, 0, 0, 0); \
    } while (0)

    // 4-deep software pipeline, named registers only (no runtime-indexed
    // arrays -> stays in VGPRs). 8 float4 loads in flight per lane.
    float4 p0l = *(const float4*)(wp + 0 * 32), p0h = *(const float4*)(wp + 0 * 32 + 4);
    float4 p1l = *(const float4*)(wp + 1 * 32), p1h = *(const float4*)(wp + 1 * 32 + 4);
    float4 p2l = *(const float4*)(wp + 2 * 32), p2h = *(const float4*)(wp + 2 * 32 + 4);
    float4 p3l = *(const float4*)(wp + 3 * 32), p3h = *(const float4*)(wp + 3 * 32 + 4);

    #pragma unroll 2
    for (int s = 0; s < STEPS; s += 4) {
        float4 lo, hi;
        lo = p0l; hi = p0h;
        if (s + 4 < STEPS) {
            p0l = *(const float4*)(wp + (s + 4) * 32);
            p0h = *(const float4*)(wp + (s + 4) * 32 + 4);
        }
        GSTEP(s + 0, lo, hi);
        lo = p1l; hi = p1h;
        if (s + 5 < STEPS) {
            p1l = *(const float4*)(wp + (s + 5) * 32);
            p1h = *(const float4*)(wp + (s + 5) * 32 + 4);
        }
        GSTEP(s + 1, lo, hi);
        lo = p2l; hi = p2h;
        if (s + 6 < STEPS) {
            p2l = *(const float4*)(wp + (s + 6) * 32);
            p2h = *(const float4*)(wp + (s + 6) * 32 + 4);
        }
        GSTEP(s + 2, lo, hi);
        lo = p3l; hi = p3h;
        if (s + 7 < STEPS) {
            p3l = *(const float4*)(wp + (s + 7) * 32);
            p3h = *(const float4*)(wp + (s + 7) * 32 + 4);
        }
        GSTEP(s + 3, lo, hi);
    }
#undef GSTEP

    // C/D layout: col = lane&15, row(t) = quad*4 + reg.
    // Plain float2 stores into this chunk's slab (each addr written once;
    // padding lanes duplicate node 0 with identical values — benign).
    float* slab = fws + (size_t)chunk * SLAB;
    #pragma unroll
    for (int r = 0; r < 4; ++r) {
        int t = quad * 4 + r;
        *(float2*)&slab[((size_t)n * T_DIM + t) * 2] = make_float2(acc0[r], acc1[r]);
    }
}

// ---------------------------------------------------------------------------
// Gather f_in = f[node_in-1] (256000 fp32, float4-vectorized: 8 threads/node)
// + boundary sums f_b (96 fp32). f = sum of the 16 chunk slabs (LLC-resident).
// ---------------------------------------------------------------------------
__global__ __launch_bounds__(256) void gather_kernel(
    const float* __restrict__ fws,
    const int* __restrict__ node_in,
    const int* __restrict__ top, const int* __restrict__ bottom,
    const int* __restrict__ left, const int* __restrict__ right,
    float* __restrict__ out)
{
    const int tid = threadIdx.x;
    if (blockIdx.x < 250) {
        int e4 = blockIdx.x * 1024 + tid * 4;  // element base; 256000 = 250*1024
        int j = e4 >> 5;                       // node_in index (32 elems/node)
        int rem = e4 & 31;                     // (t*2+o) base, 16B aligned
        size_t base = (size_t)(node_in[j] - 1) * 32 + rem;
        float4 v = {0.f, 0.f, 0.f, 0.f};
        #pragma unroll
        for (int c = 0; c < CHUNKS; ++c) {
            float4 s = *(const float4*)&fws[c * (size_t)SLAB + base];
            v.x += s.x; v.y += s.y; v.z += s.z; v.w += s.w;
        }
        *(float4*)&out[e4] = v;
    } else {
        __shared__ float red[256];
        __shared__ float sums[64];
        const int l = tid >> 6;                // 0=top 1=bottom 2=left 3=right
        const int t = (tid >> 2) & 15;
        const int p = tid & 3;
        // Select chain instead of runtime-indexed pointer array (rule #20:
        // dyn-indexed local arrays can be allocated in scratch).
        const int* lp = (l == 0) ? top : (l == 1) ? bottom : (l == 2) ? left : right;
        const int osel = (l < 2) ? 1 : 0;
        float s = 0.f;
        for (int idx = p; idx < NB; idx += 4) {
            size_t base = (size_t)(lp[idx] - 1) * 32 + t * 2 + osel;
            #pragma unroll
            for (int c = 0; c < CHUNKS; ++c) s += fws[c * (size_t)SLAB + base];
        }
        red[tid] = s;
        __syncthreads();
        if (p == 0)
            sums[tid >> 2] = red[tid] + red[tid + 1] + red[tid + 2] + red[tid + 3];
        __syncthreads();
        if (tid < 96) {
            int row = tid >> 4;                // 0..5 -> [top,bot,left,right,t+b,l+r]
            int tt = tid & 15;
            float v;
            if (row < 4)       v = sums[row * 16 + tt];
            else if (row == 4) v = sums[0 * 16 + tt] + sums[1 * 16 + tt];
            else               v = sums[2 * 16 + tt] + sums[3 * 16 + tt];
            out[256000 + tid] = v;
        }
    }
}

extern "C" void kernel_launch(void* const* d_in, const int* in_sizes, int n_in,
                              void* d_out, int out_size, void* d_ws, size_t ws_size,
                              hipStream_t stream)
{
    const float* x      = (const float*)d_in[0];
    const float* weight = (const float*)d_in[1];
    const int* node_in = (const int*)d_in[2];
    const int* top     = (const int*)d_in[3];
    const int* bottom  = (const int*)d_in[4];
    const int* left    = (const int*)d_in[5];
    const int* right   = (const int*)d_in[6];

    float* fws  = (float*)d_ws;                        // 16 slabs x 1.28 MB = 20.5 MB
    int*   cnt  = (int*)(fws + (size_t)CHUNKS * SLAB); // 1 int
    int*   list = cnt + 1;                             // up to 10000 ids
    float* out  = (float*)d_out;                       // 256000 f_in + 96 f_b

    dedup_kernel<<<1, 1024, 0, stream>>>(node_in, top, bottom, left, right, cnt, list);

    dim3 grid((TILES + 3) / 4, CHUNKS);                // 157 x 16 (worst case)
    gemm_kernel<<<grid, 256, 0, stream>>>(x, weight, list, cnt, fws);
    gather_kernel<<<251, 256, 0, stream>>>(fws, node_in, top, bottom, left, right, out);
}

// Round 6
// 461.430 us; speedup vs baseline: 1.0165x; 1.0038x over previous
//
#include <hip/hip_runtime.h>
#include <stdint.h>

// Problem constants (from reference) — all inputs/outputs are FP32.
#define T_DIM 16
#define M_DIM 1024
#define N_NODES 10000
#define NB 100
#define N_IN 8000
#define KI 4096             // i dimension (4*M)
#define KP 8192             // interleaved i' = 2*i + o (memory-contiguous axis of weight)
#define CHUNKS 16
#define I_CHUNK (KI / CHUNKS)        // 256 i-values per chunk
#define M_CHUNK (I_CHUNK / 4)        // 64 m-values per chunk
#define STEPS ((KP / CHUNKS) / 32)   // 16 MFMA k-steps per chunk
#define PITCH (I_CHUNK + 4)          // 260 shorts row pitch
#define TILES 625                    // worst-case tiles over all 10000 nodes
#define SLAB (N_NODES * T_DIM * 2)   // 320000 floats per chunk-slab

typedef short short8 __attribute__((ext_vector_type(8)));
typedef float f32x4 __attribute__((ext_vector_type(4)));

__device__ __forceinline__ unsigned int fbits(float f) {
    return __builtin_bit_cast(unsigned int, f);
}
// fp32 -> bf16 (RNE), result in low 16 bits
__device__ __forceinline__ unsigned int bf16rne(unsigned int u) {
    return (u + 0x7FFFu + ((u >> 16) & 1u)) >> 16;
}
__device__ __forceinline__ unsigned int pack2bf(float a, float b) {
    return bf16rne(fbits(a)) | (bf16rne(fbits(b)) << 16);
}
// HW packed fp32->bf16 (RNE): low16 = cvt(a), high16 = cvt(b).
__device__ __forceinline__ unsigned int cvtpk(float a, float b) {
    unsigned int r;
    asm("v_cvt_pk_bf16_f32 %0, %1, %2" : "=v"(r) : "v"(a), "v"(b));
    return r;
}

// ---------------------------------------------------------------------------
// Dedup: flag all referenced nodes in LDS, compact into a dense id list.
// Single block (1024 threads), ballot-based compaction; list comes out
// piecewise-sorted (spatial locality for the GEMM weight reads).
// ---------------------------------------------------------------------------
__global__ __launch_bounds__(1024) void dedup_kernel(
    const int* __restrict__ node_in,
    const int* __restrict__ top, const int* __restrict__ bottom,
    const int* __restrict__ left, const int* __restrict__ right,
    int* __restrict__ counter, int* __restrict__ list)
{
    __shared__ int flags[N_NODES];       // 40 KB
    __shared__ int lcnt;
    const int tid = threadIdx.x;
    for (int i = tid; i < N_NODES; i += 1024) flags[i] = 0;
    if (tid == 0) lcnt = 0;
    __syncthreads();
    for (int i = tid; i < N_IN + 4 * NB; i += 1024) {
        int v;
        if (i < N_IN)              v = node_in[i];
        else if (i < N_IN + NB)    v = top[i - N_IN];
        else if (i < N_IN + 2*NB)  v = bottom[i - N_IN - NB];
        else if (i < N_IN + 3*NB)  v = left[i - N_IN - 2*NB];
        else                       v = right[i - N_IN - 3*NB];
        flags[v - 1] = 1;
    }
    __syncthreads();
    const int lane = tid & 63;
    for (int i = tid; i < N_NODES; i += 1024) {
        int f = flags[i];
        unsigned long long mask = __ballot(f);
        int prefix = __popcll(mask & ((1ull << lane) - 1ull));
        int base = 0;
        if (lane == 0) base = atomicAdd(&lcnt, (int)__popcll(mask));
        base = __shfl(base, 0);
        if (f) list[base + prefix] = i;
    }
    __syncthreads();
    if (tid == 0) *counter = lcnt;
}

// ---------------------------------------------------------------------------
// GEMM over REFERENCED nodes only: f[n,t,o] = sum_i x_out[t,i] * W[n,i,o].
// ROUND 6 REWRITE of the B path: the old per-lane direct global reads made
// every vmem instruction a 16-node scatter (16 segments, 32 KB apart) ->
// measured ~1 TB/s effective, invariant to wave count AND pipeline depth
// (r4/r5 evidence) -> MSHR/scatter-capped. Now each wave stages its 16
// nodes' weights into LDS with PER-NODE COALESCED loads: one instruction =
// 64 lanes x 16 B = 1 KB contiguous from ONE node, converted to bf16 on the
// fly (cvtpk). The MFMA B-fragment is then a direct ds_read_b128 (already
// packed bf16 in k'-order) — the inner loop drops all global loads and all
// B-side cvtpk/unpack. LDS: 8 KB B-buffer/wave + 8.3 KB x = 41 KB/block ->
// 3 blocks/CU (12 waves) — TLP covers staging latency even if the compiler
// serializes load->ds_write pairs.
// grid = (157 tile-groups, 16 K-chunks) x 256 threads (4 waves, 1 tile each).
// ---------------------------------------------------------------------------
__global__ __launch_bounds__(256) void gemm_kernel(
    const float* __restrict__ x,       // fp32 [16][3][1024]
    const float* __restrict__ weight,  // fp32 [10000][4096][2]
    const int* __restrict__ list,      // compacted referenced node ids
    const int* __restrict__ counter,   // number of referenced nodes
    float* __restrict__ fws)           // fp32 [16][10000][16][2] partial slabs
{
    __shared__ unsigned short lds_x[T_DIM * PITCH];   // x_out chunk as bf16
    __shared__ unsigned short lds_b[4][16 * 256];     // per-wave B: 16 nodes x 256 k' bf16

    const int tid = threadIdx.x;
    const int chunk = blockIdx.y;

    const int cnt = *counter;                 // block-uniform scalar
    if (blockIdx.x * 64 >= cnt) return;       // whole block unneeded (4 waves x 16)

    // Stage this chunk's x_out[t, i] into LDS as bf16.
    // x_out[t, 4m + {0,1,2,3}] = [x[t,0,m], x[t,2,m], x[t,2,m], x[t,1,m]]
    for (int q = tid; q < T_DIM * M_CHUNK; q += 256) {
        int t = q >> 6;            // M_CHUNK == 64 per t
        int mloc = q & 63;
        int m = chunk * M_CHUNK + mloc;
        const float* xb = x + t * 3 * M_DIM + m;
        float v0 = xb[0];
        float v1 = xb[M_DIM];
        float v2 = xb[2 * M_DIM];
        unsigned int w0 = cvtpk(v0, v2);     // slots 4m+0, 4m+1
        unsigned int w1 = cvtpk(v2, v1);     // slots 4m+2, 4m+3
        *(uint2*)&lds_x[t * PITCH + mloc * 4] = make_uint2(w0, w1);
    }
    __syncthreads();

    const int wave = tid >> 6;
    const int lane = tid & 63;
    const int tile = blockIdx.x * 4 + wave;
    if (tile * 16 >= cnt) return;             // whole wave unneeded

    const int col = lane & 15;   // n-slot within tile (B/C col)
    const int quad = lane >> 4;  // k-group
    const int idx = tile * 16 + col;
    const int n = (idx < cnt) ? list[idx] : 0;

    const size_t koff = (size_t)chunk * (KP / CHUNKS);  // k' base of this chunk
    // A source: 4 consecutive bf16 x_out values for t = lane&15.
    const unsigned short* xrow = &lds_x[(lane & 15) * PITCH + quad * 4];
    unsigned short* bb = lds_b[wave];

    f32x4 acc0 = {0.f, 0.f, 0.f, 0.f};
    f32x4 acc1 = {0.f, 0.f, 0.f, 0.f};

    // Two sub-steps of 256 k' each (STEPS = 16 MFMA k-steps total).
    #pragma unroll
    for (int s = 0; s < 2; ++s) {
        // --- Stage: per node, one fully-coalesced 1 KB load (256 k' fp32),
        //     packed to bf16, written 8 B/lane (conflict-free).
        #pragma unroll
        for (int nd = 0; nd < 16; ++nd) {
            int nn = __shfl(n, nd);          // node id held by lane nd
            const float* src = weight + (size_t)nn * KP + koff + s * 256 + lane * 4;
            f32x4 w4 = *(const f32x4*)src;
            unsigned int u0 = cvtpk(w4[0], w4[1]);
            unsigned int u1 = cvtpk(w4[2], w4[3]);
            *(uint2*)&bb[nd * 256 + lane * 4] = make_uint2(u0, u1);
        }
        // (wave-private LDS region: same-wave DS ordering via lgkmcnt —
        //  compiler inserts the waits; no __syncthreads needed.)

        // --- Compute: 8 MFMA k-steps over the staged 256 k'.
        #pragma unroll
        for (int gs = 0; gs < 8; ++gs) {
            // B fragment: bf16 k' = gs*32 + quad*8 .. +7 of node `col`.
            short8 Bv = *(const short8*)&bb[col * 256 + gs * 32 + quad * 8];

            int S = s * 8 + gs;
            uint2 u = *(const uint2*)(xrow + S * 16);
            union { unsigned int ui[4]; short8 v; } A0u, A1u;
            A0u.ui[0] = u.x & 0xFFFFu;      A0u.ui[1] = u.x >> 16;
            A0u.ui[2] = u.y & 0xFFFFu;      A0u.ui[3] = u.y >> 16;
            A1u.ui[0] = u.x << 16;          A1u.ui[1] = u.x & 0xFFFF0000u;
            A1u.ui[2] = u.y << 16;          A1u.ui[3] = u.y & 0xFFFF0000u;

            acc0 = __builtin_amdgcn_mfma_f32_16x16x32_bf16(A0u.v, Bv, acc0, 0, 0, 0);
            acc1 = __builtin_amdgcn_mfma_f32_16x16x32_bf16(A1u.v, Bv, acc1, 0, 0, 0);
        }
    }

    // C/D layout: col = lane&15, row(t) = quad*4 + reg.
    // Plain float2 stores into this chunk's slab (each addr written once;
    // padding lanes duplicate node 0 with identical values — benign).
    float* slab = fws + (size_t)chunk * SLAB;
    #pragma unroll
    for (int r = 0; r < 4; ++r) {
        int t = quad * 4 + r;
        *(float2*)&slab[((size_t)n * T_DIM + t) * 2] = make_float2(acc0[r], acc1[r]);
    }
}

// ---------------------------------------------------------------------------
// Gather f_in = f[node_in-1] (256000 fp32, float4-vectorized: 8 threads/node)
// + boundary sums f_b (96 fp32). f = sum of the 16 chunk slabs (LLC-resident).
// ---------------------------------------------------------------------------
__global__ __launch_bounds__(256) void gather_kernel(
    const float* __restrict__ fws,
    const int* __restrict__ node_in,
    const int* __restrict__ top, const int* __restrict__ bottom,
    const int* __restrict__ left, const int* __restrict__ right,
    float* __restrict__ out)
{
    const int tid = threadIdx.x;
    if (blockIdx.x < 250) {
        int e4 = blockIdx.x * 1024 + tid * 4;  // element base; 256000 = 250*1024
        int j = e4 >> 5;                       // node_in index (32 elems/node)
        int rem = e4 & 31;                     // (t*2+o) base, 16B aligned
        size_t base = (size_t)(node_in[j] - 1) * 32 + rem;
        float4 v = {0.f, 0.f, 0.f, 0.f};
        #pragma unroll
        for (int c = 0; c < CHUNKS; ++c) {
            float4 s = *(const float4*)&fws[c * (size_t)SLAB + base];
            v.x += s.x; v.y += s.y; v.z += s.z; v.w += s.w;
        }
        *(float4*)&out[e4] = v;
    } else {
        __shared__ float red[256];
        __shared__ float sums[64];
        const int l = tid >> 6;                // 0=top 1=bottom 2=left 3=right
        const int t = (tid >> 2) & 15;
        const int p = tid & 3;
        // Select chain instead of runtime-indexed pointer array (rule #20).
        const int* lp = (l == 0) ? top : (l == 1) ? bottom : (l == 2) ? left : right;
        const int osel = (l < 2) ? 1 : 0;
        float s = 0.f;
        for (int idx = p; idx < NB; idx += 4) {
            size_t base = (size_t)(lp[idx] - 1) * 32 + t * 2 + osel;
            #pragma unroll
            for (int c = 0; c < CHUNKS; ++c) s += fws[c * (size_t)SLAB + base];
        }
        red[tid] = s;
        __syncthreads();
        if (p == 0)
            sums[tid >> 2] = red[tid] + red[tid + 1] + red[tid + 2] + red[tid + 3];
        __syncthreads();
        if (tid < 96) {
            int row = tid >> 4;                // 0..5 -> [top,bot,left,right,t+b,l+r]
            int tt = tid & 15;
            float v;
            if (row < 4)       v = sums[row * 16 + tt];
            else if (row == 4) v = sums[0 * 16 + tt] + sums[1 * 16 + tt];
            else               v = sums[2 * 16 + tt] + sums[3 * 16 + tt];
            out[256000 + tid] = v;
        }
    }
}

extern "C" void kernel_launch(void* const* d_in, const int* in_sizes, int n_in,
                              void* d_out, int out_size, void* d_ws, size_t ws_size,
                              hipStream_t stream)
{
    const float* x      = (const float*)d_in[0];
    const float* weight = (const float*)d_in[1];
    const int* node_in = (const int*)d_in[2];
    const int* top     = (const int*)d_in[3];
    const int* bottom  = (const int*)d_in[4];
    const int* left    = (const int*)d_in[5];
    const int* right   = (const int*)d_in[6];

    float* fws  = (float*)d_ws;                        // 16 slabs x 1.28 MB = 20.5 MB
    int*   cnt  = (int*)(fws + (size_t)CHUNKS * SLAB); // 1 int
    int*   list = cnt + 1;                             // up to 10000 ids
    float* out  = (float*)d_out;                       // 256000 f_in + 96 f_b

    dedup_kernel<<<1, 1024, 0, stream>>>(node_in, top, bottom, left, right, cnt, list);

    dim3 grid((TILES + 3) / 4, CHUNKS);                // 157 x 16 (worst case)
    gemm_kernel<<<grid, 256, 0, stream>>>(x, weight, list, cnt, fws);
    gather_kernel<<<251, 256, 0, stream>>>(fws, node_in, top, bottom, left, right, out);
}